// Round 3
// baseline (540.918 us; speedup 1.0000x reference)
//
#include <hip/hip_runtime.h>

// 2-layer tanh RNN, T=2048, B=4096, I=3, H=5. f32 storage.
//
// R8: R6 (ds_swizzle bcast) and R7 (DPP bcast) both measured ~360 cy/step
// vs ~130 cy issue+chain -> the broadcast was never the limiter. Common
// bottleneck theory: per-step inline global stores create a VMEM WAR
// hazard -- LLVM inserts s_waitcnt vmcnt(N) before the register holding
// h1n is recycled (1-2 steps later), and vmcnt drains IN ISSUE ORDER,
// stalling on store completion every step with 1 wave/SIMD (nothing to
// hide it). R5's 1-thread kernel had already solved this with a parity
// double-buffered output staging array; R6/R7 dropped it. Reinstated:
//   - ob0/ob1: per-block output staging in VGPRs, burst-flushed at block
//     end; store-data regs rewritten only 16 steps after flush issue.
//   - two NAMED arrays + twice-instantiated lambda (not obuf[blk&1]) so
//     SROA keeps both in registers (runtime first-index would go scratch).
// Compute structure unchanged from R7 (4 lanes/chain, quad_perm bcast,
// pk_fma dual-slot: lane ja owns unit ja, all lanes duplicate unit 4).
// Math is bit-identical to R7 -> absmax must stay 0.00390625.

typedef float v2f __attribute__((ext_vector_type(2)));

#define SEQ_T 2048
#define BATCH 4096
#define ISZ 3
#define HSZ 5
#define KB 8                    // steps per block (x prefetch + flush unit)
#define NBLK (SEQ_T / KB)

// broadcast lane (quad_base + K)'s value to all 4 lanes of the quad.
template<int K>
__device__ __forceinline__ float qbcast(float v) {
    return __int_as_float(__builtin_amdgcn_mov_dpp(
        __float_as_int(v), K * 0x55, 0xF, 0xF, false));
}

// input pre-scaled by S = 2*log2(e): tanh(z) = 1 - 2*rcp(1 + exp2(S*z))
__device__ __forceinline__ float tanh_fast(float a) {
    float e = __builtin_amdgcn_exp2f(a);
    return fmaf(-2.0f, __builtin_amdgcn_rcpf(1.0f + e), 1.0f);
}

__device__ __forceinline__ v2f vsplat(float s) { return (v2f){s, s}; }
__device__ __forceinline__ v2f vfma(float s, v2f w, v2f a) {
    return __builtin_elementwise_fma(vsplat(s), w, a);  // v_pk_fma_f32
}

__global__ __launch_bounds__(64, 1)
void rnn2_quad_dbuf(const float* __restrict__ x, const float* __restrict__ hx,
                    const float* __restrict__ w_ih0, const float* __restrict__ w_hh0,
                    const float* __restrict__ b_ih0, const float* __restrict__ b_hh0,
                    const float* __restrict__ w_ih1, const float* __restrict__ w_hh1,
                    const float* __restrict__ b_ih1, const float* __restrict__ b_hh1,
                    float* __restrict__ out)
{
    const int tid = threadIdx.x;
    const int c   = (blockIdx.x * 64 + tid) >> 2;   // chain id, 0..4095
    const int ja  = tid & 3;                        // slot-A unit; slot B = 4
    const float S = 2.8853900817779268f;

    // ---- weight pairs: w?p[k] = ( W[ja][k], W[4][k] ), pre-scaled by S ----
    v2f wi0p[ISZ], wh0p[HSZ], wi1p[HSZ], wh1p[HSZ];
    const v2f bias0p = (v2f){ S * (b_ih0[ja] + b_hh0[ja]), S * (b_ih0[4] + b_hh0[4]) };
    const v2f bias1p = (v2f){ S * (b_ih1[ja] + b_hh1[ja]), S * (b_ih1[4] + b_hh1[4]) };
#pragma unroll
    for (int i = 0; i < ISZ; i++)
        wi0p[i] = (v2f){ S * w_ih0[ja * ISZ + i], S * w_ih0[4 * ISZ + i] };
#pragma unroll
    for (int k = 0; k < HSZ; k++) {
        wh0p[k] = (v2f){ S * w_hh0[ja * HSZ + k], S * w_hh0[4 * HSZ + k] };
        wi1p[k] = (v2f){ S * w_ih1[ja * HSZ + k], S * w_ih1[4 * HSZ + k] };
        wh1p[k] = (v2f){ S * w_hh1[ja * HSZ + k], S * w_hh1[4 * HSZ + k] };
    }

    // ---- every lane holds the full state vectors (index 4 is lane-local) ----
    float h0b[HSZ], h1b[HSZ];
#pragma unroll
    for (int k = 0; k < HSZ; k++) {
        h0b[k] = hx[(size_t)c * HSZ + k];
        h1b[k] = hx[(size_t)BATCH * HSZ + (size_t)c * HSZ + k];
    }

    // ---- x modulo buffer: slot tt consumed, then refilled for next block ----
    const float* xp = x + (size_t)c * ISZ;
    float xbuf[KB][ISZ];
#pragma unroll
    for (int tt = 0; tt < KB; tt++)
#pragma unroll
        for (int i = 0; i < ISZ; i++)
            xbuf[tt][i] = xp[(size_t)tt * BATCH * ISZ + i];

    // lane's two output columns (lanes 1-3 dup-store unit 4: same addr+value)
    float* opA = out + (size_t)c * HSZ + ja;
    float* opB = out + (size_t)c * HSZ + 4;

    // ---- output staging: two NAMED register arrays (parity dbuf) ----
    float ob0[KB][2], ob1[KB][2];

    // one block of KB steps, computing into 'ob' (no stores inside)
    auto run_block = [&](float (&ob)[KB][2], int blk) {
        const int pf = (blk + 1 < NBLK) ? (blk + 1) * KB : blk * KB;
#pragma unroll
        for (int tt = 0; tt < KB; tt++) {
            const float xv0 = xbuf[tt][0], xv1 = xbuf[tt][1], xv2 = xbuf[tt][2];
            const float* xq = xp + (size_t)(pf + tt) * BATCH * ISZ;
            xbuf[tt][0] = xq[0]; xbuf[tt][1] = xq[1]; xbuf[tt][2] = xq[2];

            // layer 0, slots (ja, 4): accumulation order identical to R7
            v2f a = bias0p, cc = (v2f){0.0f, 0.0f};
            a  = vfma(xv0,    wi0p[0], a);
            cc = vfma(xv1,    wi0p[1], cc);
            a  = vfma(xv2,    wi0p[2], a);
            cc = vfma(h0b[0], wh0p[0], cc);
            a  = vfma(h0b[1], wh0p[1], a);
            cc = vfma(h0b[2], wh0p[2], cc);
            a  = vfma(h0b[3], wh0p[3], a);
            cc = vfma(h0b[4], wh0p[4], cc);
            a = a + cc;
            const float h0nA = tanh_fast(a.x);
            const float h0nB = tanh_fast(a.y);

            // quad broadcast (VALU DPP); unit 4 is lane-local
            h0b[0] = qbcast<0>(h0nA);
            h0b[1] = qbcast<1>(h0nA);
            h0b[2] = qbcast<2>(h0nA);
            h0b[3] = qbcast<3>(h0nA);
            h0b[4] = h0nB;

            // layer 1: reads NEW h0b, OLD h1b (Jacobi, matches reference)
            v2f d = bias1p, ee = (v2f){0.0f, 0.0f};
            d  = vfma(h0b[0], wi1p[0], d);
            ee = vfma(h0b[1], wi1p[1], ee);
            d  = vfma(h0b[2], wi1p[2], d);
            ee = vfma(h0b[3], wi1p[3], ee);
            d  = vfma(h0b[4], wi1p[4], d);
            ee = vfma(h1b[0], wh1p[0], ee);
            d  = vfma(h1b[1], wh1p[1], d);
            ee = vfma(h1b[2], wh1p[2], ee);
            d  = vfma(h1b[3], wh1p[3], d);
            ee = vfma(h1b[4], wh1p[4], ee);
            d = d + ee;
            const float h1nA = tanh_fast(d.x);
            const float h1nB = tanh_fast(d.y);

            // stage outputs in registers; NO store on the critical path
            ob[tt][0] = h1nA;
            ob[tt][1] = h1nB;

            // h1 broadcast: next use is next step's layer 1
            h1b[0] = qbcast<0>(h1nA);
            h1b[1] = qbcast<1>(h1nA);
            h1b[2] = qbcast<2>(h1nA);
            h1b[3] = qbcast<3>(h1nA);
            h1b[4] = h1nB;
        }
    };

    // burst-flush one staged block; store-data regs not rewritten for 16 steps
    auto flush_block = [&](float (&ob)[KB][2]) {
#pragma unroll
        for (int tt = 0; tt < KB; tt++) {
            *opA = ob[tt][0];
            *opB = ob[tt][1];
            opA += (size_t)BATCH * HSZ;
            opB += (size_t)BATCH * HSZ;
        }
    };

    for (int bp = 0; bp < NBLK; bp += 2) {
        run_block(ob0, bp);
        flush_block(ob0);
        run_block(ob1, bp + 1);
        flush_block(ob1);
    }

    // h_n = [h0_final, h1_final], appended after out[T,B,H].
    // h0b/h1b identical across the quad's lanes -> dup stores, benign.
    float* hn = out + (size_t)SEQ_T * BATCH * HSZ;
#pragma unroll
    for (int k = 0; k < HSZ; k++) {
        hn[(size_t)c * HSZ + k] = h0b[k];
        hn[(size_t)BATCH * HSZ + (size_t)c * HSZ + k] = h1b[k];
    }
}

extern "C" void kernel_launch(void* const* d_in, const int* in_sizes, int n_in,
                              void* d_out, int out_size, void* d_ws, size_t ws_size,
                              hipStream_t stream) {
    // 4096 chains x 4 lanes = 16384 threads; 64-thread blocks -> 256 blocks,
    // one wave per CU across all 256 CUs.
    rnn2_quad_dbuf<<<(BATCH * 4) / 64, 64, 0, stream>>>(
        (const float*)d_in[0], (const float*)d_in[1],
        (const float*)d_in[2], (const float*)d_in[3],
        (const float*)d_in[4], (const float*)d_in[5],
        (const float*)d_in[6], (const float*)d_in[7],
        (const float*)d_in[8], (const float*)d_in[9],
        (float*)d_out);
}

// Round 4
// 478.013 us; speedup vs baseline: 1.1316x; 1.1316x over previous
//
#include <hip/hip_runtime.h>

// 2-layer tanh RNN, T=2048, B=4096, I=3, H=5. f32 storage.
//
// R9: R6 (ds_swizzle), R7 (DPP), R8 (DPP+staged stores) all ~355 cy/step
// despite different cross-lane/store structure -> common bottleneck.
// Diagnosis from VGPR counts: R7 needs >=108 live floats, reports 100;
// R8 ADDED 32 staging regs and VGPR DROPPED to 72 -> the compiler is NOT
// keeping the xbuf/ob aggregates in registers; they live in scratch, and
// a ~200cy scratch load (xv0 = xbuf[tt][0]) heads every step's dependency
// chain with 1 wave/SIMD and nothing to hide it.
// Fix: ZERO aggregates. All weights/state/x-pipeline are individual named
// variables; the x prefetch is a depth-8 software pipeline rotated by an
// 8x-unrolled macro body (named regs x0*..x7*, ~900cy HBM cover). Memory
// ops use uniform SGPR base + 32-bit per-lane element offset (1 v_add_u32
// per pointer per step). Compute core is bit-identical to R7 (4 lanes per
// chain, quad_perm bcast, pk dual-slot: lane ja owns unit ja, all lanes
// duplicate unit 4) -> absmax must stay 0.00390625.

typedef float v2f __attribute__((ext_vector_type(2)));

#define SEQ_T 2048
#define BATCH 4096
#define ISZ 3
#define HSZ 5
#define PD 8                      // x pipeline depth (steps of HBM cover)
#define XSTRIDE (BATCH * ISZ)     // elements per step in x
#define OSTRIDE (BATCH * HSZ)     // elements per step in out

// broadcast lane (quad_base + K)'s value to all 4 lanes of the quad.
template<int K>
__device__ __forceinline__ float qbcast(float v) {
    return __int_as_float(__builtin_amdgcn_mov_dpp(
        __float_as_int(v), K * 0x55, 0xF, 0xF, false));
}

// input pre-scaled by S = 2*log2(e): tanh(z) = 1 - 2*rcp(1 + exp2(S*z))
__device__ __forceinline__ float tanh_fast(float a) {
    float e = __builtin_amdgcn_exp2f(a);
    return fmaf(-2.0f, __builtin_amdgcn_rcpf(1.0f + e), 1.0f);
}

__device__ __forceinline__ v2f vsplat(float s) { return (v2f){s, s}; }
__device__ __forceinline__ v2f vfma(float s, v2f w, v2f a) {
    return __builtin_elementwise_fma(vsplat(s), w, a);  // v_pk_fma_f32
}

__global__ __launch_bounds__(64, 1)
void rnn2_regs(const float* __restrict__ x, const float* __restrict__ hx,
               const float* __restrict__ w_ih0, const float* __restrict__ w_hh0,
               const float* __restrict__ b_ih0, const float* __restrict__ b_hh0,
               const float* __restrict__ w_ih1, const float* __restrict__ w_hh1,
               const float* __restrict__ b_ih1, const float* __restrict__ b_hh1,
               float* __restrict__ out)
{
    const int tid = threadIdx.x;
    const int c   = (blockIdx.x * 64 + tid) >> 2;   // chain id, 0..4095
    const int ja  = tid & 3;                        // slot-A unit; slot B = 4
    const float S = 2.8853900817779268f;

    // ---- weight pairs (ja-row, 4-row), pre-scaled by S — all NAMED ----
    const v2f bias0p = (v2f){ S * (b_ih0[ja] + b_hh0[ja]), S * (b_ih0[4] + b_hh0[4]) };
    const v2f bias1p = (v2f){ S * (b_ih1[ja] + b_hh1[ja]), S * (b_ih1[4] + b_hh1[4]) };
#define LW(W, k, n)  (v2f){ S * W[ja * (n) + (k)], S * W[4 * (n) + (k)] }
    const v2f wi0p0 = LW(w_ih0, 0, ISZ), wi0p1 = LW(w_ih0, 1, ISZ), wi0p2 = LW(w_ih0, 2, ISZ);
    const v2f wh0p0 = LW(w_hh0, 0, HSZ), wh0p1 = LW(w_hh0, 1, HSZ), wh0p2 = LW(w_hh0, 2, HSZ),
              wh0p3 = LW(w_hh0, 3, HSZ), wh0p4 = LW(w_hh0, 4, HSZ);
    const v2f wi1p0 = LW(w_ih1, 0, HSZ), wi1p1 = LW(w_ih1, 1, HSZ), wi1p2 = LW(w_ih1, 2, HSZ),
              wi1p3 = LW(w_ih1, 3, HSZ), wi1p4 = LW(w_ih1, 4, HSZ);
    const v2f wh1p0 = LW(w_hh1, 0, HSZ), wh1p1 = LW(w_hh1, 1, HSZ), wh1p2 = LW(w_hh1, 2, HSZ),
              wh1p3 = LW(w_hh1, 3, HSZ), wh1p4 = LW(w_hh1, 4, HSZ);
#undef LW

    // ---- state: named scalars (index 4 is lane-local duplicate) ----
    float h0b0 = hx[(size_t)c * HSZ + 0], h0b1 = hx[(size_t)c * HSZ + 1],
          h0b2 = hx[(size_t)c * HSZ + 2], h0b3 = hx[(size_t)c * HSZ + 3],
          h0b4 = hx[(size_t)c * HSZ + 4];
    const size_t hb1 = (size_t)BATCH * HSZ + (size_t)c * HSZ;
    float h1b0 = hx[hb1 + 0], h1b1 = hx[hb1 + 1], h1b2 = hx[hb1 + 2],
          h1b3 = hx[hb1 + 3], h1b4 = hx[hb1 + 4];

    // ---- x pipeline: depth PD=8, 24 NAMED floats ----
    unsigned xoff = (unsigned)c * ISZ;              // element offset into x
    float x0a = x[xoff + 0*XSTRIDE], x0b = x[xoff + 0*XSTRIDE + 1], x0c = x[xoff + 0*XSTRIDE + 2];
    float x1a = x[xoff + 1*XSTRIDE], x1b = x[xoff + 1*XSTRIDE + 1], x1c = x[xoff + 1*XSTRIDE + 2];
    float x2a = x[xoff + 2*XSTRIDE], x2b = x[xoff + 2*XSTRIDE + 1], x2c = x[xoff + 2*XSTRIDE + 2];
    float x3a = x[xoff + 3*XSTRIDE], x3b = x[xoff + 3*XSTRIDE + 1], x3c = x[xoff + 3*XSTRIDE + 2];
    float x4a = x[xoff + 4*XSTRIDE], x4b = x[xoff + 4*XSTRIDE + 1], x4c = x[xoff + 4*XSTRIDE + 2];
    float x5a = x[xoff + 5*XSTRIDE], x5b = x[xoff + 5*XSTRIDE + 1], x5c = x[xoff + 5*XSTRIDE + 2];
    float x6a = x[xoff + 6*XSTRIDE], x6b = x[xoff + 6*XSTRIDE + 1], x6c = x[xoff + 6*XSTRIDE + 2];
    float x7a = x[xoff + 7*XSTRIDE], x7b = x[xoff + 7*XSTRIDE + 1], x7c = x[xoff + 7*XSTRIDE + 2];
    xoff += PD * XSTRIDE;                           // next load target: step 8

    // ---- output offsets (32-bit element offsets off uniform base) ----
    unsigned ooffA = (unsigned)c * HSZ + (unsigned)ja;
    unsigned ooffB = (unsigned)c * HSZ + 4u;

    // One RNN step. Consumes (XV0,XV1,XV2); if DOLOAD, refills them with
    // x[t+8] and advances xoff. Math order identical to R7.
#define CORE(XV0, XV1, XV2, DOLOAD)                                        \
    {                                                                      \
        const float xv0 = XV0, xv1 = XV1, xv2 = XV2;                       \
        if (DOLOAD) {                                                      \
            XV0 = x[xoff]; XV1 = x[xoff + 1]; XV2 = x[xoff + 2];           \
            xoff += XSTRIDE;                                               \
        }                                                                  \
        v2f a = bias0p, cc = (v2f){0.0f, 0.0f};                            \
        a  = vfma(xv0,  wi0p0, a);                                         \
        cc = vfma(xv1,  wi0p1, cc);                                        \
        a  = vfma(xv2,  wi0p2, a);                                         \
        cc = vfma(h0b0, wh0p0, cc);                                        \
        a  = vfma(h0b1, wh0p1, a);                                         \
        cc = vfma(h0b2, wh0p2, cc);                                        \
        a  = vfma(h0b3, wh0p3, a);                                         \
        cc = vfma(h0b4, wh0p4, cc);                                        \
        a = a + cc;                                                        \
        const float h0nA = tanh_fast(a.x);                                 \
        const float h0nB = tanh_fast(a.y);                                 \
        h0b0 = qbcast<0>(h0nA);                                            \
        h0b1 = qbcast<1>(h0nA);                                            \
        h0b2 = qbcast<2>(h0nA);                                            \
        h0b3 = qbcast<3>(h0nA);                                            \
        h0b4 = h0nB;                                                       \
        v2f d = bias1p, ee = (v2f){0.0f, 0.0f};                            \
        d  = vfma(h0b0, wi1p0, d);                                         \
        ee = vfma(h0b1, wi1p1, ee);                                        \
        d  = vfma(h0b2, wi1p2, d);                                         \
        ee = vfma(h0b3, wi1p3, ee);                                        \
        d  = vfma(h0b4, wi1p4, d);                                         \
        ee = vfma(h1b0, wh1p0, ee);                                        \
        d  = vfma(h1b1, wh1p1, d);                                         \
        ee = vfma(h1b2, wh1p2, ee);                                        \
        d  = vfma(h1b3, wh1p3, d);                                         \
        ee = vfma(h1b4, wh1p4, ee);                                        \
        d = d + ee;                                                        \
        const float h1nA = tanh_fast(d.x);                                 \
        const float h1nB = tanh_fast(d.y);                                 \
        out[ooffA] = h1nA;                                                 \
        out[ooffB] = h1nB;                                                 \
        ooffA += OSTRIDE;                                                  \
        ooffB += OSTRIDE;                                                  \
        h1b0 = qbcast<0>(h1nA);                                            \
        h1b1 = qbcast<1>(h1nA);                                            \
        h1b2 = qbcast<2>(h1nA);                                            \
        h1b3 = qbcast<3>(h1nA);                                            \
        h1b4 = h1nB;                                                       \
    }

    // main: (T/PD - 1) x 8 steps with prefetch; epilogue: 8 steps, no loads
    for (int it = 0; it < SEQ_T / PD - 1; ++it) {
        CORE(x0a, x0b, x0c, 1)
        CORE(x1a, x1b, x1c, 1)
        CORE(x2a, x2b, x2c, 1)
        CORE(x3a, x3b, x3c, 1)
        CORE(x4a, x4b, x4c, 1)
        CORE(x5a, x5b, x5c, 1)
        CORE(x6a, x6b, x6c, 1)
        CORE(x7a, x7b, x7c, 1)
    }
    CORE(x0a, x0b, x0c, 0)
    CORE(x1a, x1b, x1c, 0)
    CORE(x2a, x2b, x2c, 0)
    CORE(x3a, x3b, x3c, 0)
    CORE(x4a, x4b, x4c, 0)
    CORE(x5a, x5b, x5c, 0)
    CORE(x6a, x6b, x6c, 0)
    CORE(x7a, x7b, x7c, 0)
#undef CORE

    // h_n = [h0_final, h1_final], appended after out[T,B,H].
    // State identical across the quad's lanes -> dup stores, benign.
    float* hn = out + (size_t)SEQ_T * BATCH * HSZ;
    hn[(size_t)c * HSZ + 0] = h0b0;
    hn[(size_t)c * HSZ + 1] = h0b1;
    hn[(size_t)c * HSZ + 2] = h0b2;
    hn[(size_t)c * HSZ + 3] = h0b3;
    hn[(size_t)c * HSZ + 4] = h0b4;
    hn[hb1 + 0] = h1b0;
    hn[hb1 + 1] = h1b1;
    hn[hb1 + 2] = h1b2;
    hn[hb1 + 3] = h1b3;
    hn[hb1 + 4] = h1b4;
}

extern "C" void kernel_launch(void* const* d_in, const int* in_sizes, int n_in,
                              void* d_out, int out_size, void* d_ws, size_t ws_size,
                              hipStream_t stream) {
    // 4096 chains x 4 lanes = 16384 threads; 64-thread blocks -> 256 blocks,
    // one wave per CU across all 256 CUs.
    rnn2_regs<<<(BATCH * 4) / 64, 64, 0, stream>>>(
        (const float*)d_in[0], (const float*)d_in[1],
        (const float*)d_in[2], (const float*)d_in[3],
        (const float*)d_in[4], (const float*)d_in[5],
        (const float*)d_in[6], (const float*)d_in[7],
        (const float*)d_in[8], (const float*)d_in[9],
        (float*)d_out);
}